// Round 14
// baseline (700.329 us; speedup 1.0000x reference)
//
#include <hip/hip_runtime.h>
#include <hip/hip_bf16.h>

typedef __attribute__((ext_vector_type(8))) short short8;
typedef __attribute__((ext_vector_type(4))) float f32x4;
typedef unsigned short ushort_t;
typedef __attribute__((ext_vector_type(2))) unsigned short ushort2v;
typedef __attribute__((ext_vector_type(2))) unsigned int uint2v;
typedef __attribute__((ext_vector_type(4))) unsigned int uint4v;

static __device__ __forceinline__ ushort_t f2bf(float x) {
    __hip_bfloat16 h = __float2bfloat16(x);
    return *(ushort_t*)&h;
}
static __device__ __forceinline__ float bflo(unsigned int u) { return __uint_as_float(u << 16); }
static __device__ __forceinline__ float bfhi(unsigned int u) { return __uint_as_float(u & 0xffff0000u); }

// DPP cross-lane adds (VALU pipe). quad_perm xor1=0xB1, xor2=0x4E.
template <int CTRL>
static __device__ __forceinline__ float dpp_xadd(float x) {
    int y = __builtin_amdgcn_update_dpp(0, __float_as_int(x), CTRL, 0xF, 0xF, true);
    return x + __int_as_float(y);
}
// lane^4 add via ds_swizzle (1 DS op)
static __device__ __forceinline__ float swz4_add(float x) {
    int y = __builtin_amdgcn_ds_swizzle(__float_as_int(x), 0x101F);
    return x + __int_as_float(y);
}

// ---------------------------------------------------------------------------
// GraphTransformer: 3x TransformerConv(H=8,c=16) + BN/ReLU, fixed graph.
// ---------------------------------------------------------------------------

// ---------------- CSR build ----------------
__global__ void hist_kernel(const int* __restrict__ dst, int E, int* __restrict__ hist) {
    int i = blockIdx.x * blockDim.x + threadIdx.x;
    if (i < E) atomicAdd(&hist[dst[i]], 1);
}

__global__ __launch_bounds__(1024) void scan_block_kernel(
    const int* __restrict__ hist, int n, int* __restrict__ row_ptr, int* __restrict__ bsums)
{
    __shared__ int lds[1024];
    int tid = threadIdx.x;
    int i = blockIdx.x * 1024 + tid;
    int vv = (i < n) ? hist[i] : 0;
    lds[tid] = vv;
    __syncthreads();
    for (int off = 1; off < 1024; off <<= 1) {
        int t = (tid >= off) ? lds[tid - off] : 0;
        __syncthreads();
        lds[tid] += t;
        __syncthreads();
    }
    if (i < n) row_ptr[i] = lds[tid] - vv;
    if (tid == 1023) bsums[blockIdx.x] = lds[1023];
}

__global__ void scan_tops_kernel(int* __restrict__ bsums, int nb) {
    if (threadIdx.x == 0 && blockIdx.x == 0) {
        int run = 0;
        for (int i = 0; i < nb; i++) { int t = bsums[i]; bsums[i] = run; run += t; }
    }
}

__global__ __launch_bounds__(256) void scan_add_kernel(
    const int* __restrict__ bsums, int n, int total,
    int* __restrict__ row_ptr, int* __restrict__ cursor)
{
    int i = blockIdx.x * blockDim.x + threadIdx.x;
    if (i < n) {
        int vv = row_ptr[i] + bsums[i >> 10];
        row_ptr[i] = vv;
        cursor[i] = vv;
    }
    if (i == 0) row_ptr[n] = total;
}

__global__ void scatter_kernel(const int* __restrict__ src, const int* __restrict__ dst, int E,
                               int* __restrict__ cursor, int* __restrict__ inv, int* __restrict__ srcs) {
    int i = blockIdx.x * blockDim.x + threadIdx.x;
    if (i < E) {
        int d = dst[i];
        int pos = atomicAdd(&cursor[d], 1);
        inv[i] = pos;
        srcs[pos] = src[i];
    }
}

// ---------------- combined: passthrough copy + permuted bf16 ea ----------------
__global__ __launch_bounds__(256) void copy_permute_kernel(
    const float* __restrict__ edge_attr, const int* __restrict__ inv, int E,
    float* __restrict__ out_pass, ushort_t* __restrict__ ea)
{
    int idx = blockIdx.x * blockDim.x + threadIdx.x;
    if (idx >= E * 8) return;
    int i = idx >> 3, seg = idx & 7;
    const float* s = edge_attr + (size_t)i * 64 + seg * 8;
    float4 f0 = *(const float4*)s;
    float4 f1 = *(const float4*)(s + 4);
    float* d = out_pass + (size_t)i * 64 + seg * 8;
    *(float4*)d = f0;
    *(float4*)(d + 4) = f1;
    short8 o;
    o[0] = f2bf(f0.x); o[1] = f2bf(f0.y); o[2] = f2bf(f0.z); o[3] = f2bf(f0.w);
    o[4] = f2bf(f1.x); o[5] = f2bf(f1.y); o[6] = f2bf(f1.z); o[7] = f2bf(f1.w);
    int pos = inv[i];
    *(short8*)(ea + (size_t)pos * 64 + seg * 8) = o;
}

// ---------------- unified weight packing (1 launch) ----------------
struct PackArgs {
    const float* We[3];
    const float* Wn[3][4];   // Wq,Wk,Wv,Ws per layer
    const float* bb[3][4];   // bq,bk,bv,bs per layer
};

__global__ __launch_bounds__(256) void pack_all_kernel(
    PackArgs pa, ushort_t* __restrict__ BpackE, ushort_t* __restrict__ BpackN,
    float* __restrict__ biasc)
{
    int idx = blockIdx.x * blockDim.x + threadIdx.x;
    if (idx < 24576) {
        // edge weights: 3 x 8192
        int j = idx & 7, lane = (idx >> 3) & 63, kk = (idx >> 9) & 1,
            t = (idx >> 10) & 7, layer = idx >> 13;
        int kdim = kk * 32 + (lane >> 4) * 8 + j;
        int ncol = t * 16 + (lane & 15);
        BpackE[idx] = f2bf(pa.We[layer][kdim * 128 + ncol]);
    } else if (idx < 188416) {
        // node weights: l0 32768 (DI=64), l1/l2 65536 (DI=128)
        int local = idx - 24576;
        int layer, DI;
        if (local < 32768) { layer = 0; DI = 64; }
        else if (local < 98304) { layer = 1; DI = 128; local -= 32768; }
        else { layer = 2; DI = 128; local -= 98304; }
        int NKF = DI >> 5;
        int j = local & 7, lane = (local >> 3) & 63;
        int rest = local >> 9;
        int kf = rest % NKF, t = rest / NKF;
        int kdim = kf * 32 + (lane >> 4) * 8 + j;
        int ncol = t * 16 + (lane & 15);
        BpackN[layer * 65536 + local] = f2bf(pa.Wn[layer][ncol >> 7][kdim * 128 + (ncol & 127)]);
    } else if (idx < 189952) {
        int local = idx - 188416;
        int layer = local >> 9, i = local & 511;
        biasc[layer * 512 + i] = pa.bb[layer][i >> 7][i & 127];
    }
}

// ---------------- fused node GEMM via MFMA (+ inline BN/ReLU of input) ------
template <int DI, bool BN>
__global__ __launch_bounds__(256) void node_gemm_mfma_kernel(
    const float* __restrict__ hin, int N,
    const ushort_t* __restrict__ Bpack, const float* __restrict__ biasc,
    const float* __restrict__ scale, const float* __restrict__ shift,
    float* __restrict__ qout, unsigned int* __restrict__ kvout,
    float* __restrict__ skipout)
{
    constexpr int NKF = DI / 32;
    __shared__ float ctile[64][132];
    __shared__ ushort_t ctileK[64][136];
    int wave = threadIdx.x >> 6;
    int lane = threadIdx.x & 63;
    int tid = threadIdx.x;
    int base = blockIdx.x * 64;
    int m0 = base + wave * 16;

    int mrow = min(m0 + (lane & 15), N - 1);
    const float* arow = hin + (size_t)mrow * DI;
    int koff = (lane >> 4) * 8;

    short8 a[NKF];
#pragma unroll
    for (int kf = 0; kf < NKF; kf++) {
        float4 fa = *(const float4*)(arow + kf * 32 + koff);
        float4 fb = *(const float4*)(arow + kf * 32 + koff + 4);
        if constexpr (BN) {
            int c0 = kf * 32 + koff;
            float4 sa = *(const float4*)(scale + c0);
            float4 sb = *(const float4*)(scale + c0 + 4);
            float4 ha = *(const float4*)(shift + c0);
            float4 hb = *(const float4*)(shift + c0 + 4);
            fa.x = fmaxf(fa.x * sa.x + ha.x, 0.f);
            fa.y = fmaxf(fa.y * sa.y + ha.y, 0.f);
            fa.z = fmaxf(fa.z * sa.z + ha.z, 0.f);
            fa.w = fmaxf(fa.w * sa.w + ha.w, 0.f);
            fb.x = fmaxf(fb.x * sb.x + hb.x, 0.f);
            fb.y = fmaxf(fb.y * sb.y + hb.y, 0.f);
            fb.z = fmaxf(fb.z * sb.z + hb.z, 0.f);
            fb.w = fmaxf(fb.w * sb.w + hb.w, 0.f);
        }
        short8 t;
        t[0] = f2bf(fa.x); t[1] = f2bf(fa.y); t[2] = f2bf(fa.z); t[3] = f2bf(fa.w);
        t[4] = f2bf(fb.x); t[5] = f2bf(fb.y); t[6] = f2bf(fb.z); t[7] = f2bf(fb.w);
        a[kf] = t;
    }

    const short8* Bp = (const short8*)Bpack;
    f32x4 acc[32];
#pragma unroll
    for (int t = 0; t < 32; t++) acc[t] = (f32x4){0.f, 0.f, 0.f, 0.f};
#pragma unroll
    for (int t = 0; t < 32; t++) {
#pragma unroll
        for (int kf = 0; kf < NKF; kf++)
            acc[t] = __builtin_amdgcn_mfma_f32_16x16x32_bf16(a[kf], Bp[(t * NKF + kf) * 64 + lane], acc[t], 0, 0, 0);
    }

    int crow = (lane >> 4) * 4;
    int ccol = lane & 15;

    // ---- q ----
#pragma unroll
    for (int t8 = 0; t8 < 8; t8++) {
        float bb = biasc[t8 * 16 + ccol];
#pragma unroll
        for (int r = 0; r < 4; r++)
            ctile[wave * 16 + crow + r][t8 * 16 + ccol] = acc[t8][r] + bb;
    }
    __syncthreads();
#pragma unroll
    for (int it = 0; it < 8; it++) {
        int idx4 = it * 256 + tid;
        int row = idx4 >> 5;
        int c4 = idx4 & 31;
        int gr = base + row;
        if (gr < N)
            *(float4*)(qout + (size_t)gr * 128 + c4 * 4) = *(const float4*)&ctile[row][c4 * 4];
    }
    __syncthreads();

    // ---- k -> ctileK (bf16), v -> ctile ----
#pragma unroll
    for (int t8 = 0; t8 < 8; t8++) {
        float bb = biasc[128 + t8 * 16 + ccol];
#pragma unroll
        for (int r = 0; r < 4; r++)
            ctileK[wave * 16 + crow + r][t8 * 16 + ccol] = f2bf(acc[8 + t8][r] + bb);
    }
#pragma unroll
    for (int t8 = 0; t8 < 8; t8++) {
        float bb = biasc[256 + t8 * 16 + ccol];
#pragma unroll
        for (int r = 0; r < 4; r++)
            ctile[wave * 16 + crow + r][t8 * 16 + ccol] = acc[16 + t8][r] + bb;
    }
    __syncthreads();
    // emit pair-interleaved kv: u32 slot 2*c2 = k-pair, 2*c2+1 = v-pair
#pragma unroll
    for (int it = 0; it < 4; it++) {
        int idx8 = it * 256 + tid;
        int row = idx8 >> 4;
        int c8 = idx8 & 15;
        int gr = base + row;
        if (gr < N) {
            const float* vs = &ctile[row][c8 * 8];
            uint4v o0, o1;
#pragma unroll
            for (int i = 0; i < 4; i++) {
                ushort2v kp2 = *(const ushort2v*)&ctileK[row][c8 * 8 + 2 * i];
                unsigned int kp = (unsigned int)kp2[0] | ((unsigned int)kp2[1] << 16);
                unsigned int vp = (unsigned int)f2bf(vs[2 * i]) | ((unsigned int)f2bf(vs[2 * i + 1]) << 16);
                if (i < 2) { o0[2 * i] = kp; o0[2 * i + 1] = vp; }
                else       { o1[2 * (i - 2)] = kp; o1[2 * (i - 2) + 1] = vp; }
            }
            unsigned int* dp = kvout + (size_t)gr * 128 + c8 * 8;
            *(uint4v*)dp = o0;
            *(uint4v*)(dp + 4) = o1;
        }
    }
    __syncthreads();

    // ---- skip ----
#pragma unroll
    for (int t8 = 0; t8 < 8; t8++) {
        float bb = biasc[384 + t8 * 16 + ccol];
#pragma unroll
        for (int r = 0; r < 4; r++)
            ctile[wave * 16 + crow + r][t8 * 16 + ccol] = acc[24 + t8][r] + bb;
    }
    __syncthreads();
#pragma unroll
    for (int it = 0; it < 8; it++) {
        int idx4 = it * 256 + tid;
        int row = idx4 >> 5;
        int c4 = idx4 & 31;
        int gr = base + row;
        if (gr < N)
            *(float4*)(skipout + (size_t)gr * 128 + c4 * 4) = *(const float4*)&ctile[row][c4 * 4];
    }
}

// ---------------- fused aggregation (f32 e-tile in LDS) ----------------
#define PROCESS8(B)                                                              \
    {                                                                            \
        float2 eef[8];                                                           \
        float p[8];                                                              \
        _Pragma("unroll")                                                        \
        for (int u = 0; u < 8; u++)                                              \
            eef[u] = *(const float2*)&elds[wave][(B) * 8 + u][2 * lane];         \
        _Pragma("unroll")                                                        \
        for (int u = 0; u < 8; u++) {                                            \
            uint2v kvp = kvr[(B) * 8 + u];                                       \
            p[u] = qq.x * (bflo(kvp[0]) + eef[u].x)                              \
                 + qq.y * (bfhi(kvp[0]) + eef[u].y);                             \
        }                                                                        \
        _Pragma("unroll")                                                        \
        for (int u = 0; u < 8; u++) {                                            \
            p[u] = dpp_xadd<0xB1>(p[u]);                                         \
            p[u] = dpp_xadd<0x4E>(p[u]);                                         \
            p[u] = swz4_add(p[u]);                                               \
        }                                                                        \
        _Pragma("unroll")                                                        \
        for (int u = 0; u < 8; u++) {                                            \
            float wv = __expf(fminf(p[u], 60.0f));                               \
            if (c0 + (B) * 8 + u >= je) wv = 0.f;                                \
            uint2v kvp = kvr[(B) * 8 + u];                                       \
            acc0 += wv * (bflo(kvp[1]) + eef[u].x);                              \
            acc1 += wv * (bfhi(kvp[1]) + eef[u].y);                              \
            sw += wv;                                                            \
        }                                                                        \
    }

__global__ __launch_bounds__(256) void agg_fused_kernel(
    const int* __restrict__ row_ptr, const int* __restrict__ srcs,
    const float* __restrict__ q, const unsigned int* __restrict__ kvbuf,
    const ushort_t* __restrict__ ea, const ushort_t* __restrict__ BpackWe,
    float* __restrict__ hout, int N)
{
    __shared__ ushort_t bsh[8192];            // We fragments, 16 KB
    __shared__ float elds[4][16][132];        // per-wave e tile, f32 (33.8 KB)
    int tid = threadIdx.x;
    {
        const short8* s8 = (const short8*)BpackWe;
        short8* d8 = (short8*)bsh;
#pragma unroll
        for (int i = 0; i < 4; i++) d8[i * 256 + tid] = s8[i * 256 + tid];
    }
    __syncthreads();

    int wave = tid >> 6, lane = tid & 63;
    int n = blockIdx.x * 4 + wave;
    if (n >= N) return;

    const float2* q2 = (const float2*)q;
    float2* h2 = (float2*)hout;
    const short8* bs8 = (const short8*)bsh;

    int ch = lane & 15, kg = lane >> 4;
    float2 qq = q2[(size_t)n * 64 + lane];
    qq.x *= 0.25f; qq.y *= 0.25f;             // fold 1/sqrt(16)
    float2 sk = h2[(size_t)n * 64 + lane];
    float acc0 = 0.f, acc1 = 0.f, sw = 0.f;
    int jb = row_ptr[n], je = row_ptr[n + 1];

    short8 a0 = {}, a1 = {};
    int sv = 0;
    if (jb < je) {
        int j0 = min(jb + ch, je - 1);
        sv = srcs[j0];
        const ushort_t* row0 = ea + (size_t)j0 * 64;
        a0 = *(const short8*)(row0 + kg * 8);
        a1 = *(const short8*)(row0 + 32 + kg * 8);
    }

    for (int c0 = jb; c0 < je; c0 += 16) {
        // issue all 16 kv gathers first (readlane -> uniform SGPR base)
        uint2v kvr[16];
#pragma unroll
        for (int u = 0; u < 16; u++) {
            int su = __builtin_amdgcn_readlane(sv, u);
            kvr[u] = *(const uint2v*)(kvbuf + (size_t)su * 128 + 2 * lane);
        }

        // e_tile[16 edges][128 ch] = A @ We (C: row=kg*4+r, col=t*16+ch), f32
#pragma unroll
        for (int t = 0; t < 8; t++) {
            f32x4 z = (f32x4){0.f, 0.f, 0.f, 0.f};
            z = __builtin_amdgcn_mfma_f32_16x16x32_bf16(a0, bs8[(t * 2 + 0) * 64 + lane], z, 0, 0, 0);
            z = __builtin_amdgcn_mfma_f32_16x16x32_bf16(a1, bs8[(t * 2 + 1) * 64 + lane], z, 0, 0, 0);
#pragma unroll
            for (int r = 0; r < 4; r++)
                elds[wave][kg * 4 + r][t * 16 + ch] = z[r];
        }

        // prefetch next chunk's ea fragments + srcs
        int cn = c0 + 16;
        short8 na0 = a0, na1 = a1;
        int nsv = sv;
        if (cn < je) {
            int jn = min(cn + ch, je - 1);
            nsv = srcs[jn];
            const ushort_t* nrow = ea + (size_t)jn * 64;
            na0 = *(const short8*)(nrow + kg * 8);
            na1 = *(const short8*)(nrow + 32 + kg * 8);
        }

        // compiler fence: elds writes must not sink past the reads below;
        // HW DS pipe is in-order per wave.
        asm volatile("" ::: "memory");

        PROCESS8(0)
        if (c0 + 8 < je) PROCESS8(1)

        a0 = na0; a1 = na1; sv = nsv;
    }
    float inv = 1.0f / (sw + 1e-16f);
    float2 o;
    o.x = acc0 * inv + sk.x;
    o.y = acc1 * inv + sk.y;
    h2[(size_t)n * 64 + lane] = o;
}

// ---------------- BatchNorm stats + finalize ----------------
__global__ __launch_bounds__(128) void bn_stats_kernel(const float* __restrict__ h, int N,
                                                       float* __restrict__ sums) {
    int f = threadIdx.x;
    float s = 0.f, s2 = 0.f;
    for (int n = blockIdx.x; n < N; n += gridDim.x) {
        float x = h[(size_t)n * 128 + f];
        s += x;
        s2 += x * x;
    }
    atomicAdd(&sums[f], s);
    atomicAdd(&sums[128 + f], s2);
}

__global__ __launch_bounds__(128) void bn_finalize_kernel(
    const float* __restrict__ sums, const float* __restrict__ g,
    const float* __restrict__ be, int N,
    float* __restrict__ scale, float* __restrict__ shift)
{
    int f = threadIdx.x;
    float invN = 1.0f / (float)N;
    float mu = sums[f] * invN;
    float var = sums[128 + f] * invN - mu * mu;
    float sc = g[f] * rsqrtf(var + 1e-5f);
    scale[f] = sc;
    shift[f] = be[f] - mu * sc;
}

// ---------------------------------------------------------------------------
extern "C" void kernel_launch(void* const* d_in, const int* in_sizes, int n_in,
                              void* d_out, int out_size, void* d_ws, size_t ws_size,
                              hipStream_t stream)
{
    const float* x = (const float*)d_in[0];
    const int* edge_index = (const int*)d_in[1];
    const float* edge_attr = (const float*)d_in[2];
    int N = in_sizes[0] / 64;
    int E = in_sizes[1] / 2;
    const int* src = edge_index;
    const int* dst = edge_index + E;

    const float* W[3][9];
    for (int l = 0; l < 3; l++)
        for (int i = 0; i < 9; i++) W[l][i] = (const float*)d_in[3 + l * 9 + i];
    // 0:Wq 1:bq 2:Wk 3:bk 4:Wv 5:bv 6:We 7:Ws 8:bs
    const float* g0 = (const float*)d_in[30];
    const float* be0 = (const float*)d_in[31];
    const float* g1 = (const float*)d_in[32];
    const float* be1 = (const float*)d_in[33];

    char* p = (char*)d_ws;
    auto alloc = [&](size_t bytes) -> char* {
        char* r = p;
        p += (bytes + 255) & ~(size_t)255;
        return r;
    };
    float* q = (float*)alloc((size_t)N * 128 * 4);
    unsigned int* kvbuf = (unsigned int*)alloc((size_t)N * 512);
    float* B = (float*)alloc((size_t)N * 128 * 4);
    ushort_t* ea = (ushort_t*)alloc((size_t)E * 64 * 2);
    int* row_ptr = (int*)alloc((size_t)(N + 1) * 4);
    int* cursor = (int*)alloc((size_t)N * 4);
    int* histb = (int*)alloc((size_t)N * 4);
    int* inv = (int*)alloc((size_t)E * 4);
    int* srcs = (int*)alloc((size_t)E * 4);
    int* bsums = (int*)alloc(64 * 4);
    float* sums = (float*)alloc(512 * 4);     // 2 layers x 256
    float* bnp = (float*)alloc(512 * 4);      // scale0|shift0|scale1|shift1
    ushort_t* BpackE = (ushort_t*)alloc((size_t)3 * 8192 * 2);
    ushort_t* BpackN = (ushort_t*)alloc((size_t)3 * 65536 * 2);
    float* biasc = (float*)alloc((size_t)3 * 512 * 4);

    int nb = (N + 1023) / 1024;

    // ---- CSR build (parallel scan) ----
    hipMemsetAsync(histb, 0, (size_t)N * 4, stream);
    hipMemsetAsync(sums, 0, 512 * 4, stream);
    hist_kernel<<<(E + 255) / 256, 256, 0, stream>>>(dst, E, histb);
    scan_block_kernel<<<nb, 1024, 0, stream>>>(histb, N, row_ptr, bsums);
    scan_tops_kernel<<<1, 64, 0, stream>>>(bsums, nb);
    scan_add_kernel<<<(N + 255) / 256, 256, 0, stream>>>(bsums, N, E, row_ptr, cursor);
    scatter_kernel<<<(E + 255) / 256, 256, 0, stream>>>(src, dst, E, cursor, inv, srcs);
    // passthrough copy + permuted bf16 ea in one pass
    copy_permute_kernel<<<(E * 8 + 255) / 256, 256, 0, stream>>>(
        edge_attr, inv, E, (float*)d_out + (size_t)N * 128, ea);

    // ---- unified weight packing ----
    {
        PackArgs pa;
        for (int l = 0; l < 3; l++) {
            pa.We[l] = W[l][6];
            pa.Wn[l][0] = W[l][0]; pa.Wn[l][1] = W[l][2];
            pa.Wn[l][2] = W[l][4]; pa.Wn[l][3] = W[l][7];
            pa.bb[l][0] = W[l][1]; pa.bb[l][1] = W[l][3];
            pa.bb[l][2] = W[l][5]; pa.bb[l][3] = W[l][8];
        }
        pack_all_kernel<<<(189952 + 255) / 256, 256, 0, stream>>>(pa, BpackE, BpackN, biasc);
    }

    for (int l = 0; l < 3; l++) {
        float* skipbuf = (l == 2) ? (float*)d_out : B;
        if (l == 0)
            node_gemm_mfma_kernel<64, false><<<(N + 63) / 64, 256, 0, stream>>>(
                x, N, BpackN, biasc, nullptr, nullptr, q, kvbuf, skipbuf);
        else
            node_gemm_mfma_kernel<128, true><<<(N + 63) / 64, 256, 0, stream>>>(
                B, N, BpackN + (size_t)l * 65536, biasc + (size_t)l * 512,
                bnp + (size_t)(l - 1) * 256, bnp + (size_t)(l - 1) * 256 + 128,
                q, kvbuf, skipbuf);
        agg_fused_kernel<<<(N + 3) / 4, 256, 0, stream>>>(
            row_ptr, srcs, q, kvbuf, ea, BpackE + (size_t)l * 8192, skipbuf, N);
        if (l < 2) {
            bn_stats_kernel<<<512, 128, 0, stream>>>(skipbuf, N, sums + (size_t)l * 256);
            const float* gg = (l == 0) ? g0 : g1;
            const float* bb = (l == 0) ? be0 : be1;
            bn_finalize_kernel<<<1, 128, 0, stream>>>(
                sums + (size_t)l * 256, gg, bb, N,
                bnp + (size_t)l * 256, bnp + (size_t)l * 256 + 128);
        }
    }
}

// Round 15
// 656.362 us; speedup vs baseline: 1.0670x; 1.0670x over previous
//
#include <hip/hip_runtime.h>
#include <hip/hip_bf16.h>

typedef __attribute__((ext_vector_type(8))) short short8;
typedef __attribute__((ext_vector_type(4))) float f32x4;
typedef unsigned short ushort_t;
typedef __attribute__((ext_vector_type(2))) unsigned short ushort2v;
typedef __attribute__((ext_vector_type(2))) unsigned int uint2v;
typedef __attribute__((ext_vector_type(4))) unsigned int uint4v;

static __device__ __forceinline__ ushort_t f2bf(float x) {
    __hip_bfloat16 h = __float2bfloat16(x);
    return *(ushort_t*)&h;
}
static __device__ __forceinline__ float bflo(unsigned int u) { return __uint_as_float(u << 16); }
static __device__ __forceinline__ float bfhi(unsigned int u) { return __uint_as_float(u & 0xffff0000u); }
static __device__ __forceinline__ float bfu(ushort_t u) { return __uint_as_float((unsigned int)u << 16); }

// DPP cross-lane adds (VALU pipe). quad_perm xor1=0xB1, xor2=0x4E.
template <int CTRL>
static __device__ __forceinline__ float dpp_xadd(float x) {
    int y = __builtin_amdgcn_update_dpp(0, __float_as_int(x), CTRL, 0xF, 0xF, true);
    return x + __int_as_float(y);
}
// lane^4 add via ds_swizzle (1 DS op)
static __device__ __forceinline__ float swz4_add(float x) {
    int y = __builtin_amdgcn_ds_swizzle(__float_as_int(x), 0x101F);
    return x + __int_as_float(y);
}

// ---------------------------------------------------------------------------
// GraphTransformer: 3x TransformerConv(H=8,c=16) + BN/ReLU, fixed graph.
// ---------------------------------------------------------------------------

// ---------------- CSR build ----------------
__global__ void hist_kernel(const int* __restrict__ dst, int E, int* __restrict__ hist) {
    int i = blockIdx.x * blockDim.x + threadIdx.x;
    if (i < E) atomicAdd(&hist[dst[i]], 1);
}

__global__ __launch_bounds__(1024) void scan_block_kernel(
    const int* __restrict__ hist, int n, int* __restrict__ row_ptr, int* __restrict__ bsums)
{
    __shared__ int lds[1024];
    int tid = threadIdx.x;
    int i = blockIdx.x * 1024 + tid;
    int vv = (i < n) ? hist[i] : 0;
    lds[tid] = vv;
    __syncthreads();
    for (int off = 1; off < 1024; off <<= 1) {
        int t = (tid >= off) ? lds[tid - off] : 0;
        __syncthreads();
        lds[tid] += t;
        __syncthreads();
    }
    if (i < n) row_ptr[i] = lds[tid] - vv;
    if (tid == 1023) bsums[blockIdx.x] = lds[1023];
}

__global__ void scan_tops_kernel(int* __restrict__ bsums, int nb) {
    if (threadIdx.x == 0 && blockIdx.x == 0) {
        int run = 0;
        for (int i = 0; i < nb; i++) { int t = bsums[i]; bsums[i] = run; run += t; }
    }
}

__global__ __launch_bounds__(256) void scan_add_kernel(
    const int* __restrict__ bsums, int n, int total,
    int* __restrict__ row_ptr, int* __restrict__ cursor)
{
    int i = blockIdx.x * blockDim.x + threadIdx.x;
    if (i < n) {
        int vv = row_ptr[i] + bsums[i >> 10];
        row_ptr[i] = vv;
        cursor[i] = vv;
    }
    if (i == 0) row_ptr[n] = total;
}

__global__ void scatter_kernel(const int* __restrict__ src, const int* __restrict__ dst, int E,
                               int* __restrict__ cursor, int* __restrict__ inv, int* __restrict__ srcs) {
    int i = blockIdx.x * blockDim.x + threadIdx.x;
    if (i < E) {
        int d = dst[i];
        int pos = atomicAdd(&cursor[d], 1);
        inv[i] = pos;
        srcs[pos] = src[i];
    }
}

// ---------------- combined: passthrough copy + permuted bf16 ea ----------------
__global__ __launch_bounds__(256) void copy_permute_kernel(
    const float* __restrict__ edge_attr, const int* __restrict__ inv, int E,
    float* __restrict__ out_pass, ushort_t* __restrict__ ea)
{
    int idx = blockIdx.x * blockDim.x + threadIdx.x;
    if (idx >= E * 8) return;
    int i = idx >> 3, seg = idx & 7;
    const float* s = edge_attr + (size_t)i * 64 + seg * 8;
    float4 f0 = *(const float4*)s;
    float4 f1 = *(const float4*)(s + 4);
    float* d = out_pass + (size_t)i * 64 + seg * 8;
    *(float4*)d = f0;
    *(float4*)(d + 4) = f1;
    short8 o;
    o[0] = f2bf(f0.x); o[1] = f2bf(f0.y); o[2] = f2bf(f0.z); o[3] = f2bf(f0.w);
    o[4] = f2bf(f1.x); o[5] = f2bf(f1.y); o[6] = f2bf(f1.z); o[7] = f2bf(f1.w);
    int pos = inv[i];
    *(short8*)(ea + (size_t)pos * 64 + seg * 8) = o;
}

// ---------------- unified weight packing (1 launch) ----------------
struct PackArgs {
    const float* We[3];
    const float* Wn[3][4];   // Wq,Wk,Wv,Ws per layer
    const float* bb[3][4];   // bq,bk,bv,bs per layer
};

__global__ __launch_bounds__(256) void pack_all_kernel(
    PackArgs pa, ushort_t* __restrict__ BpackE, ushort_t* __restrict__ BpackN,
    float* __restrict__ biasc)
{
    int idx = blockIdx.x * blockDim.x + threadIdx.x;
    if (idx < 24576) {
        // edge weights: 3 x 8192
        int j = idx & 7, lane = (idx >> 3) & 63, kk = (idx >> 9) & 1,
            t = (idx >> 10) & 7, layer = idx >> 13;
        int kdim = kk * 32 + (lane >> 4) * 8 + j;
        int ncol = t * 16 + (lane & 15);
        BpackE[idx] = f2bf(pa.We[layer][kdim * 128 + ncol]);
    } else if (idx < 188416) {
        // node weights: l0 32768 (DI=64), l1/l2 65536 (DI=128)
        int local = idx - 24576;
        int layer, DI;
        if (local < 32768) { layer = 0; DI = 64; }
        else if (local < 98304) { layer = 1; DI = 128; local -= 32768; }
        else { layer = 2; DI = 128; local -= 98304; }
        int NKF = DI >> 5;
        int j = local & 7, lane = (local >> 3) & 63;
        int rest = local >> 9;
        int kf = rest % NKF, t = rest / NKF;
        int kdim = kf * 32 + (lane >> 4) * 8 + j;
        int ncol = t * 16 + (lane & 15);
        BpackN[layer * 65536 + local] = f2bf(pa.Wn[layer][ncol >> 7][kdim * 128 + (ncol & 127)]);
    } else if (idx < 189952) {
        int local = idx - 188416;
        int layer = local >> 9, i = local & 511;
        biasc[layer * 512 + i] = pa.bb[layer][i >> 7][i & 127];
    }
}

// ---------------- fused node GEMM via MFMA (+ inline BN/ReLU of input) ------
template <int DI, bool BN>
__global__ __launch_bounds__(256) void node_gemm_mfma_kernel(
    const float* __restrict__ hin, int N,
    const ushort_t* __restrict__ Bpack, const float* __restrict__ biasc,
    const float* __restrict__ scale, const float* __restrict__ shift,
    float* __restrict__ qout, unsigned int* __restrict__ kvout,
    float* __restrict__ skipout)
{
    constexpr int NKF = DI / 32;
    __shared__ float ctile[64][132];
    __shared__ ushort_t ctileK[64][136];
    int wave = threadIdx.x >> 6;
    int lane = threadIdx.x & 63;
    int tid = threadIdx.x;
    int base = blockIdx.x * 64;
    int m0 = base + wave * 16;

    int mrow = min(m0 + (lane & 15), N - 1);
    const float* arow = hin + (size_t)mrow * DI;
    int koff = (lane >> 4) * 8;

    short8 a[NKF];
#pragma unroll
    for (int kf = 0; kf < NKF; kf++) {
        float4 fa = *(const float4*)(arow + kf * 32 + koff);
        float4 fb = *(const float4*)(arow + kf * 32 + koff + 4);
        if constexpr (BN) {
            int c0 = kf * 32 + koff;
            float4 sa = *(const float4*)(scale + c0);
            float4 sb = *(const float4*)(scale + c0 + 4);
            float4 ha = *(const float4*)(shift + c0);
            float4 hb = *(const float4*)(shift + c0 + 4);
            fa.x = fmaxf(fa.x * sa.x + ha.x, 0.f);
            fa.y = fmaxf(fa.y * sa.y + ha.y, 0.f);
            fa.z = fmaxf(fa.z * sa.z + ha.z, 0.f);
            fa.w = fmaxf(fa.w * sa.w + ha.w, 0.f);
            fb.x = fmaxf(fb.x * sb.x + hb.x, 0.f);
            fb.y = fmaxf(fb.y * sb.y + hb.y, 0.f);
            fb.z = fmaxf(fb.z * sb.z + hb.z, 0.f);
            fb.w = fmaxf(fb.w * sb.w + hb.w, 0.f);
        }
        short8 t;
        t[0] = f2bf(fa.x); t[1] = f2bf(fa.y); t[2] = f2bf(fa.z); t[3] = f2bf(fa.w);
        t[4] = f2bf(fb.x); t[5] = f2bf(fb.y); t[6] = f2bf(fb.z); t[7] = f2bf(fb.w);
        a[kf] = t;
    }

    const short8* Bp = (const short8*)Bpack;
    f32x4 acc[32];
#pragma unroll
    for (int t = 0; t < 32; t++) acc[t] = (f32x4){0.f, 0.f, 0.f, 0.f};
#pragma unroll
    for (int t = 0; t < 32; t++) {
#pragma unroll
        for (int kf = 0; kf < NKF; kf++)
            acc[t] = __builtin_amdgcn_mfma_f32_16x16x32_bf16(a[kf], Bp[(t * NKF + kf) * 64 + lane], acc[t], 0, 0, 0);
    }

    int crow = (lane >> 4) * 4;
    int ccol = lane & 15;

    // ---- q ----
#pragma unroll
    for (int t8 = 0; t8 < 8; t8++) {
        float bb = biasc[t8 * 16 + ccol];
#pragma unroll
        for (int r = 0; r < 4; r++)
            ctile[wave * 16 + crow + r][t8 * 16 + ccol] = acc[t8][r] + bb;
    }
    __syncthreads();
#pragma unroll
    for (int it = 0; it < 8; it++) {
        int idx4 = it * 256 + tid;
        int row = idx4 >> 5;
        int c4 = idx4 & 31;
        int gr = base + row;
        if (gr < N)
            *(float4*)(qout + (size_t)gr * 128 + c4 * 4) = *(const float4*)&ctile[row][c4 * 4];
    }
    __syncthreads();

    // ---- k -> ctileK (bf16), v -> ctile ----
#pragma unroll
    for (int t8 = 0; t8 < 8; t8++) {
        float bb = biasc[128 + t8 * 16 + ccol];
#pragma unroll
        for (int r = 0; r < 4; r++)
            ctileK[wave * 16 + crow + r][t8 * 16 + ccol] = f2bf(acc[8 + t8][r] + bb);
    }
#pragma unroll
    for (int t8 = 0; t8 < 8; t8++) {
        float bb = biasc[256 + t8 * 16 + ccol];
#pragma unroll
        for (int r = 0; r < 4; r++)
            ctile[wave * 16 + crow + r][t8 * 16 + ccol] = acc[16 + t8][r] + bb;
    }
    __syncthreads();
    // emit pair-interleaved kv: u32 slot 2*c2 = k-pair, 2*c2+1 = v-pair
#pragma unroll
    for (int it = 0; it < 4; it++) {
        int idx8 = it * 256 + tid;
        int row = idx8 >> 4;
        int c8 = idx8 & 15;
        int gr = base + row;
        if (gr < N) {
            const float* vs = &ctile[row][c8 * 8];
            uint4v o0, o1;
#pragma unroll
            for (int i = 0; i < 4; i++) {
                ushort2v kp2 = *(const ushort2v*)&ctileK[row][c8 * 8 + 2 * i];
                unsigned int kp = (unsigned int)kp2[0] | ((unsigned int)kp2[1] << 16);
                unsigned int vp = (unsigned int)f2bf(vs[2 * i]) | ((unsigned int)f2bf(vs[2 * i + 1]) << 16);
                if (i < 2) { o0[2 * i] = kp; o0[2 * i + 1] = vp; }
                else       { o1[2 * (i - 2)] = kp; o1[2 * (i - 2) + 1] = vp; }
            }
            unsigned int* dp = kvout + (size_t)gr * 128 + c8 * 8;
            *(uint4v*)dp = o0;
            *(uint4v*)(dp + 4) = o1;
        }
    }
    __syncthreads();

    // ---- skip ----
#pragma unroll
    for (int t8 = 0; t8 < 8; t8++) {
        float bb = biasc[384 + t8 * 16 + ccol];
#pragma unroll
        for (int r = 0; r < 4; r++)
            ctile[wave * 16 + crow + r][t8 * 16 + ccol] = acc[24 + t8][r] + bb;
    }
    __syncthreads();
#pragma unroll
    for (int it = 0; it < 8; it++) {
        int idx4 = it * 256 + tid;
        int row = idx4 >> 5;
        int c4 = idx4 & 31;
        int gr = base + row;
        if (gr < N)
            *(float4*)(skipout + (size_t)gr * 128 + c4 * 4) = *(const float4*)&ctile[row][c4 * 4];
    }
}

// ---------------- fused aggregation (r13 measured-best configuration) -------
#define PROCESS8(B)                                                              \
    {                                                                            \
        ushort2v eev[8];                                                         \
        float p[8];                                                              \
        _Pragma("unroll")                                                        \
        for (int u = 0; u < 8; u++)                                              \
            eev[u] = *(const ushort2v*)&elds[wave][(B) * 8 + u][2 * lane];       \
        _Pragma("unroll")                                                        \
        for (int u = 0; u < 8; u++) {                                            \
            uint2v kvp = kvr[(B) * 8 + u];                                       \
            p[u] = qq.x * (bflo(kvp[0]) + bfu(eev[u][0]))                        \
                 + qq.y * (bfhi(kvp[0]) + bfu(eev[u][1]));                       \
        }                                                                        \
        _Pragma("unroll")                                                        \
        for (int u = 0; u < 8; u++) {                                            \
            p[u] = dpp_xadd<0xB1>(p[u]);                                         \
            p[u] = dpp_xadd<0x4E>(p[u]);                                         \
            p[u] = swz4_add(p[u]);                                               \
        }                                                                        \
        _Pragma("unroll")                                                        \
        for (int u = 0; u < 8; u++) {                                            \
            float wv = __expf(p[u]);                                             \
            if (c0 + (B) * 8 + u >= je) wv = 0.f;                                \
            uint2v kvp = kvr[(B) * 8 + u];                                       \
            acc0 += wv * (bflo(kvp[1]) + bfu(eev[u][0]));                        \
            acc1 += wv * (bfhi(kvp[1]) + bfu(eev[u][1]));                        \
            sw += wv;                                                            \
        }                                                                        \
    }

__global__ __launch_bounds__(512) void agg_fused_kernel(
    const int* __restrict__ row_ptr, const int* __restrict__ srcs,
    const float* __restrict__ q, const unsigned int* __restrict__ kvbuf,
    const ushort_t* __restrict__ ea, const ushort_t* __restrict__ BpackWe,
    float* __restrict__ hout, int N)
{
    __shared__ ushort_t bsh[8192];            // We fragments, 16 KB
    __shared__ ushort_t elds[8][16][136];     // per-wave e tile (34.8 KB)
    int tid = threadIdx.x;
    {
        const short8* s8 = (const short8*)BpackWe;
        short8* d8 = (short8*)bsh;
        d8[tid] = s8[tid];
        d8[512 + tid] = s8[512 + tid];
    }
    __syncthreads();

    int wave = tid >> 6, lane = tid & 63;
    int n = blockIdx.x * 8 + wave;
    if (n >= N) return;

    const float2* q2 = (const float2*)q;
    float2* h2 = (float2*)hout;
    const short8* bs8 = (const short8*)bsh;

    int ch = lane & 15, kg = lane >> 4;
    float2 qq = q2[(size_t)n * 64 + lane];
    qq.x *= 0.25f; qq.y *= 0.25f;             // fold 1/sqrt(16) into q
    float2 sk = h2[(size_t)n * 64 + lane];
    float acc0 = 0.f, acc1 = 0.f, sw = 0.f;
    int jb = row_ptr[n], je = row_ptr[n + 1];

    short8 a0 = {}, a1 = {};
    int sv = 0;
    if (jb < je) {
        int j0 = min(jb + ch, je - 1);
        sv = srcs[j0];
        const ushort_t* row0 = ea + (size_t)j0 * 64;
        a0 = *(const short8*)(row0 + kg * 8);
        a1 = *(const short8*)(row0 + 32 + kg * 8);
    }

    for (int c0 = jb; c0 < je; c0 += 16) {
        // issue all 16 kv gathers first (readlane -> uniform SGPR base)
        uint2v kvr[16];
#pragma unroll
        for (int u = 0; u < 16; u++) {
            int su = __builtin_amdgcn_readlane(sv, u);
            kvr[u] = *(const uint2v*)(kvbuf + (size_t)su * 128 + 2 * lane);
        }

        // e_tile[16 edges][128 ch] = A @ We (C: row=kg*4+r, col=t*16+ch)
#pragma unroll
        for (int t = 0; t < 8; t++) {
            f32x4 z = (f32x4){0.f, 0.f, 0.f, 0.f};
            z = __builtin_amdgcn_mfma_f32_16x16x32_bf16(a0, bs8[(t * 2 + 0) * 64 + lane], z, 0, 0, 0);
            z = __builtin_amdgcn_mfma_f32_16x16x32_bf16(a1, bs8[(t * 2 + 1) * 64 + lane], z, 0, 0, 0);
#pragma unroll
            for (int r = 0; r < 4; r++)
                elds[wave][kg * 4 + r][t * 16 + ch] = f2bf(z[r]);
        }

        // prefetch next chunk's ea fragments + srcs
        int cn = c0 + 16;
        short8 na0 = a0, na1 = a1;
        int nsv = sv;
        if (cn < je) {
            int jn = min(cn + ch, je - 1);
            nsv = srcs[jn];
            const ushort_t* nrow = ea + (size_t)jn * 64;
            na0 = *(const short8*)(nrow + kg * 8);
            na1 = *(const short8*)(nrow + 32 + kg * 8);
        }

        // compiler fence: elds writes must not sink past the reads below;
        // HW DS pipe is in-order per wave.
        asm volatile("" ::: "memory");

        PROCESS8(0)
        if (c0 + 8 < je) PROCESS8(1)

        a0 = na0; a1 = na1; sv = nsv;
    }
    float inv = 1.0f / (sw + 1e-16f);
    float2 o;
    o.x = acc0 * inv + sk.x;
    o.y = acc1 * inv + sk.y;
    h2[(size_t)n * 64 + lane] = o;
}

// ---------------- BatchNorm stats + finalize ----------------
__global__ __launch_bounds__(128) void bn_stats_kernel(const float* __restrict__ h, int N,
                                                       float* __restrict__ sums) {
    int f = threadIdx.x;
    float s = 0.f, s2 = 0.f;
    for (int n = blockIdx.x; n < N; n += gridDim.x) {
        float x = h[(size_t)n * 128 + f];
        s += x;
        s2 += x * x;
    }
    atomicAdd(&sums[f], s);
    atomicAdd(&sums[128 + f], s2);
}

__global__ __launch_bounds__(128) void bn_finalize_kernel(
    const float* __restrict__ sums, const float* __restrict__ g,
    const float* __restrict__ be, int N,
    float* __restrict__ scale, float* __restrict__ shift)
{
    int f = threadIdx.x;
    float invN = 1.0f / (float)N;
    float mu = sums[f] * invN;
    float var = sums[128 + f] * invN - mu * mu;
    float sc = g[f] * rsqrtf(var + 1e-5f);
    scale[f] = sc;
    shift[f] = be[f] - mu * sc;
}

// ---------------------------------------------------------------------------
extern "C" void kernel_launch(void* const* d_in, const int* in_sizes, int n_in,
                              void* d_out, int out_size, void* d_ws, size_t ws_size,
                              hipStream_t stream)
{
    const float* x = (const float*)d_in[0];
    const int* edge_index = (const int*)d_in[1];
    const float* edge_attr = (const float*)d_in[2];
    int N = in_sizes[0] / 64;
    int E = in_sizes[1] / 2;
    const int* src = edge_index;
    const int* dst = edge_index + E;

    const float* W[3][9];
    for (int l = 0; l < 3; l++)
        for (int i = 0; i < 9; i++) W[l][i] = (const float*)d_in[3 + l * 9 + i];
    // 0:Wq 1:bq 2:Wk 3:bk 4:Wv 5:bv 6:We 7:Ws 8:bs
    const float* g0 = (const float*)d_in[30];
    const float* be0 = (const float*)d_in[31];
    const float* g1 = (const float*)d_in[32];
    const float* be1 = (const float*)d_in[33];

    char* p = (char*)d_ws;
    auto alloc = [&](size_t bytes) -> char* {
        char* r = p;
        p += (bytes + 255) & ~(size_t)255;
        return r;
    };
    float* q = (float*)alloc((size_t)N * 128 * 4);
    unsigned int* kvbuf = (unsigned int*)alloc((size_t)N * 512);
    float* B = (float*)alloc((size_t)N * 128 * 4);
    ushort_t* ea = (ushort_t*)alloc((size_t)E * 64 * 2);
    int* row_ptr = (int*)alloc((size_t)(N + 1) * 4);
    int* cursor = (int*)alloc((size_t)N * 4);
    int* histb = (int*)alloc((size_t)N * 4);
    int* inv = (int*)alloc((size_t)E * 4);
    int* srcs = (int*)alloc((size_t)E * 4);
    int* bsums = (int*)alloc(64 * 4);
    float* sums = (float*)alloc(512 * 4);     // 2 layers x 256
    float* bnp = (float*)alloc(512 * 4);      // scale0|shift0|scale1|shift1
    ushort_t* BpackE = (ushort_t*)alloc((size_t)3 * 8192 * 2);
    ushort_t* BpackN = (ushort_t*)alloc((size_t)3 * 65536 * 2);
    float* biasc = (float*)alloc((size_t)3 * 512 * 4);

    int nb = (N + 1023) / 1024;

    // ---- CSR build (parallel scan) ----
    hipMemsetAsync(histb, 0, (size_t)N * 4, stream);
    hipMemsetAsync(sums, 0, 512 * 4, stream);
    hist_kernel<<<(E + 255) / 256, 256, 0, stream>>>(dst, E, histb);
    scan_block_kernel<<<nb, 1024, 0, stream>>>(histb, N, row_ptr, bsums);
    scan_tops_kernel<<<1, 64, 0, stream>>>(bsums, nb);
    scan_add_kernel<<<(N + 255) / 256, 256, 0, stream>>>(bsums, N, E, row_ptr, cursor);
    scatter_kernel<<<(E + 255) / 256, 256, 0, stream>>>(src, dst, E, cursor, inv, srcs);
    // passthrough copy + permuted bf16 ea in one pass
    copy_permute_kernel<<<(E * 8 + 255) / 256, 256, 0, stream>>>(
        edge_attr, inv, E, (float*)d_out + (size_t)N * 128, ea);

    // ---- unified weight packing ----
    {
        PackArgs pa;
        for (int l = 0; l < 3; l++) {
            pa.We[l] = W[l][6];
            pa.Wn[l][0] = W[l][0]; pa.Wn[l][1] = W[l][2];
            pa.Wn[l][2] = W[l][4]; pa.Wn[l][3] = W[l][7];
            pa.bb[l][0] = W[l][1]; pa.bb[l][1] = W[l][3];
            pa.bb[l][2] = W[l][5]; pa.bb[l][3] = W[l][8];
        }
        pack_all_kernel<<<(189952 + 255) / 256, 256, 0, stream>>>(pa, BpackE, BpackN, biasc);
    }

    for (int l = 0; l < 3; l++) {
        float* skipbuf = (l == 2) ? (float*)d_out : B;
        if (l == 0)
            node_gemm_mfma_kernel<64, false><<<(N + 63) / 64, 256, 0, stream>>>(
                x, N, BpackN, biasc, nullptr, nullptr, q, kvbuf, skipbuf);
        else
            node_gemm_mfma_kernel<128, true><<<(N + 63) / 64, 256, 0, stream>>>(
                B, N, BpackN + (size_t)l * 65536, biasc + (size_t)l * 512,
                bnp + (size_t)(l - 1) * 256, bnp + (size_t)(l - 1) * 256 + 128,
                q, kvbuf, skipbuf);
        agg_fused_kernel<<<(N + 7) / 8, 512, 0, stream>>>(
            row_ptr, srcs, q, kvbuf, ea, BpackE + (size_t)l * 8192, skipbuf, N);
        if (l < 2) {
            bn_stats_kernel<<<512, 128, 0, stream>>>(skipbuf, N, sums + (size_t)l * 256);
            const float* gg = (l == 0) ? g0 : g1;
            const float* bb = (l == 0) ? be0 : be1;
            bn_finalize_kernel<<<1, 128, 0, stream>>>(
                sums + (size_t)l * 256, gg, bb, N,
                bnp + (size_t)l * 256, bnp + (size_t)l * 256 + 128);
        }
    }
}